// Round 6
// baseline (177.580 us; speedup 1.0000x reference)
//
#include <hip/hip_runtime.h>
#include <math.h>

#define N_TOK 8192
#define DIM   2048
#define NE    64
#define TOPK  4
#define THETA 2e-3f
#define TPB2  32                      /* tokens per k_main block */
#define NBLK  (N_TOK / TPB2)          /* 256 */
#define RSTR  516                     /* padded LDS row stride (floats), 512-k window */

typedef short bf16x8 __attribute__((ext_vector_type(8)));
typedef float f32x4  __attribute__((ext_vector_type(4)));

// ---- workspace layout (float offsets) ----
#define OFF_LOGITS 0                          /* N_TOK*NE = 524288 */
#define OFF_MAXV   (OFF_LOGITS + N_TOK * NE)
#define OFF_DENOM  (OFF_MAXV + N_TOK)
#define OFF_W1     (OFF_DENOM + N_TOK)
#define OFF_C1     (OFF_W1 + N_TOK)           /* int */
#define OFF_NFLAG  (OFF_C1 + N_TOK)           /* int (padded 64) */
#define OFF_GHIST  (OFF_NFLAG + 64)           /* int, NE (padded 64) */
#define OFF_FLAGL  (OFF_GHIST + 64)           /* int, N_TOK */
#define OFF_WH     (OFF_FLAGL + N_TOK)        /* NE*DIM bf16, frag-packed */
#define OFF_WL     (OFF_WH + NE * DIM / 2)
#define OFF_WT     (OFF_WL + NE * DIM / 2)    /* NE*DIM fp32 transposed */
#define OFF_WTMP   (OFF_WT + NE * DIM)        /* N_TOK*TOPK */

// pack 2 fp32 -> 2 truncated bf16 (hi) and 2 truncated bf16 of residual (lo)
__device__ inline void cvt2(float a, float b, unsigned& hi, unsigned& lo) {
    const unsigned ua = __float_as_uint(a), ub = __float_as_uint(b);
    hi = __builtin_amdgcn_perm(ub, ua, 0x07060302u);   // [a_hi16, b_hi16]
    const float ra = a - __uint_as_float(ua & 0xFFFF0000u);
    const float rb = b - __uint_as_float(ub & 0xFFFF0000u);
    lo = __builtin_amdgcn_perm(__float_as_uint(rb), __float_as_uint(ra), 0x07060302u);
}

union FragU { unsigned u[4]; bf16x8 v; uint4 q; };

__device__ inline void make_frags(const float4& p, const float4& q,
                                  bf16x8& hi, bf16x8& lo) {
    FragU H, L;
    cvt2(p.x, p.y, H.u[0], L.u[0]);
    cvt2(p.z, p.w, H.u[1], L.u[1]);
    cvt2(q.x, q.y, H.u[2], L.u[2]);
    cvt2(q.z, q.w, H.u[3], L.u[3]);
    hi = H.v; lo = L.v;
}

// W -> frag-packed (wh2, wl2): element for (kc, nt, lane, j) is
// W[e = nt*16 + (lane&15)][k = kc*32 + (lane>>4)*8 + j] at elem offset
// (kc*4+nt)*512 + lane*8 + j. Also wt fp32 transpose [k][e]; zero nflag/ghist.
__global__ __launch_bounds__(256)
void k_wc(const float* __restrict__ W, unsigned short* __restrict__ wh2,
          unsigned short* __restrict__ wl2, float* __restrict__ wt,
          int* __restrict__ nflag, int* __restrict__ ghist) {
    const int t = blockIdx.x * 256 + threadIdx.x;     // 0..16383
    if (t < NE) ghist[t] = 0;
    if (t == NE) nflag[0] = 0;
    const int l  = t & 63;
    const int grp = t >> 6;                           // = kc*4 + nt, 0..255
    const int nt = grp & 3;
    const int kc = grp >> 2;
    const int e  = nt * 16 + (l & 15);
    const int k0 = kc * 32 + (l >> 4) * 8;

    const float4 p = *reinterpret_cast<const float4*>(W + (size_t)e * DIM + k0);
    const float4 q = *reinterpret_cast<const float4*>(W + (size_t)e * DIM + k0 + 4);
    FragU H, L;
    cvt2(p.x, p.y, H.u[0], L.u[0]);
    cvt2(p.z, p.w, H.u[1], L.u[1]);
    cvt2(q.x, q.y, H.u[2], L.u[2]);
    cvt2(q.z, q.w, H.u[3], L.u[3]);
    const size_t off = (size_t)grp * 512 + l * 8;
    *reinterpret_cast<uint4*>(wh2 + off) = H.q;
    *reinterpret_cast<uint4*>(wl2 + off) = L.q;

    wt[(size_t)(k0 + 0) * NE + e] = p.x;
    wt[(size_t)(k0 + 1) * NE + e] = p.y;
    wt[(size_t)(k0 + 2) * NE + e] = p.z;
    wt[(size_t)(k0 + 3) * NE + e] = p.w;
    wt[(size_t)(k0 + 4) * NE + e] = q.x;
    wt[(size_t)(k0 + 5) * NE + e] = q.y;
    wt[(size_t)(k0 + 6) * NE + e] = q.z;
    wt[(size_t)(k0 + 7) * NE + e] = q.w;
}

// Fused split-bf16 MFMA GEMM + stats. 1024 thr (16 waves), 32 tokens/block.
// Window = 512 k staged in LDS; wave w owns k-chunk win*512 + w*32; each wave
// computes 2 M-tiles (tokens m, m+16). 3 MFMA products (al*bl dropped).
// Reduction: strips s_w + s_{w+8} in-register, then sequential 8-strip sum.
__global__ __launch_bounds__(1024, 4)
void k_main(const float* __restrict__ x, const unsigned short* __restrict__ wh2,
            const unsigned short* __restrict__ wl2, const float* __restrict__ bias,
            float* __restrict__ logits, float* __restrict__ maxv,
            float* __restrict__ denomv, float* __restrict__ w1f,
            int* __restrict__ c1, int* __restrict__ nflag, int* __restrict__ flagl,
            int* __restrict__ ghist) {
    __shared__ __align__(16) float xs[TPB2 * RSTR];   // 66048 B
    __shared__ float red[8][TPB2][68];                 // 69632 B
    __shared__ float lbuf[TPB2][68];                   //  8704 B

    const int tid = threadIdx.x;
    const int w   = tid >> 6;            // wave 0..15
    const int l   = tid & 63;
    const int t0  = blockIdx.x * TPB2;
    const int m   = l & 15;
    const int g   = l >> 4;

    // staging map: thread covers 16B of row srow, 4 column chunks 512B apart
    const int srow = tid >> 5;           // 0..31
    const int sc   = tid & 31;
    const float* xsrc = x + (size_t)(t0 + srow) * DIM + sc * 4;
    float* sdst = &xs[srow * RSTR + sc * 4];

    // B: elem offset ((win*16+w)*4+nt)*512 + l*8
    const unsigned short* bh = wh2 + (size_t)w * 2048 + l * 8;
    const unsigned short* bl = wl2 + (size_t)w * 2048 + l * 8;

    f32x4 acc[2][4];
    #pragma unroll
    for (int mt = 0; mt < 2; ++mt)
        #pragma unroll
        for (int nt = 0; nt < 4; ++nt)
            #pragma unroll
            for (int r = 0; r < 4; ++r) acc[mt][nt][r] = 0.0f;

    // prologue: stage window 0
    float4 pf[4];
    #pragma unroll
    for (int j = 0; j < 4; ++j)
        pf[j] = *reinterpret_cast<const float4*>(xsrc + j * 128);
    #pragma unroll
    for (int j = 0; j < 4; ++j)
        *reinterpret_cast<float4*>(sdst + j * 128) = pf[j];
    __syncthreads();

    const int aoff = m * RSTR + w * 32 + g * 8;

    #pragma unroll
    for (int win = 0; win < 4; ++win) {
        if (win < 3) {
            #pragma unroll
            for (int j = 0; j < 4; ++j)
                pf[j] = *reinterpret_cast<const float4*>(
                    xsrc + (size_t)(win + 1) * 512 + j * 128);
        }
        uint4 BH[4], BL[4];
        #pragma unroll
        for (int nt = 0; nt < 4; ++nt) {
            BH[nt] = *reinterpret_cast<const uint4*>(bh + (size_t)win * 32768 + nt * 512);
            BL[nt] = *reinterpret_cast<const uint4*>(bl + (size_t)win * 32768 + nt * 512);
        }
        const float4 p0 = *reinterpret_cast<const float4*>(&xs[aoff]);
        const float4 q0 = *reinterpret_cast<const float4*>(&xs[aoff + 4]);
        const float4 p1 = *reinterpret_cast<const float4*>(&xs[aoff + 16 * RSTR]);
        const float4 q1 = *reinterpret_cast<const float4*>(&xs[aoff + 16 * RSTR + 4]);
        bf16x8 ah0, al0, ah1, al1;
        make_frags(p0, q0, ah0, al0);
        make_frags(p1, q1, ah1, al1);

        #pragma unroll
        for (int nt = 0; nt < 4; ++nt) {
            FragU b; b.q = BH[nt];
            acc[0][nt] = __builtin_amdgcn_mfma_f32_16x16x32_bf16(ah0, b.v, acc[0][nt], 0, 0, 0);
            acc[1][nt] = __builtin_amdgcn_mfma_f32_16x16x32_bf16(ah1, b.v, acc[1][nt], 0, 0, 0);
            acc[0][nt] = __builtin_amdgcn_mfma_f32_16x16x32_bf16(al0, b.v, acc[0][nt], 0, 0, 0);
            acc[1][nt] = __builtin_amdgcn_mfma_f32_16x16x32_bf16(al1, b.v, acc[1][nt], 0, 0, 0);
        }
        #pragma unroll
        for (int nt = 0; nt < 4; ++nt) {
            FragU b; b.q = BL[nt];
            acc[0][nt] = __builtin_amdgcn_mfma_f32_16x16x32_bf16(ah0, b.v, acc[0][nt], 0, 0, 0);
            acc[1][nt] = __builtin_amdgcn_mfma_f32_16x16x32_bf16(ah1, b.v, acc[1][nt], 0, 0, 0);
        }
        __syncthreads();
        if (win < 3) {
            #pragma unroll
            for (int j = 0; j < 4; ++j)
                *reinterpret_cast<float4*>(sdst + j * 128) = pf[j];
            __syncthreads();
        }
    }

    // pair-combine strips: c_w = s_w + s_{w+8}, then sequential sum over 8
    if (w >= 8) {
        #pragma unroll
        for (int mt = 0; mt < 2; ++mt)
            #pragma unroll
            for (int nt = 0; nt < 4; ++nt)
                #pragma unroll
                for (int r = 0; r < 4; ++r)
                    red[w - 8][mt * 16 + g * 4 + r][nt * 16 + m] = acc[mt][nt][r];
    }
    __syncthreads();
    if (w < 8) {
        #pragma unroll
        for (int mt = 0; mt < 2; ++mt)
            #pragma unroll
            for (int nt = 0; nt < 4; ++nt)
                #pragma unroll
                for (int r = 0; r < 4; ++r)
                    acc[mt][nt][r] += red[w][mt * 16 + g * 4 + r][nt * 16 + m];
    }
    __syncthreads();
    if (w < 8) {
        #pragma unroll
        for (int mt = 0; mt < 2; ++mt)
            #pragma unroll
            for (int nt = 0; nt < 4; ++nt)
                #pragma unroll
                for (int r = 0; r < 4; ++r)
                    red[w][mt * 16 + g * 4 + r][nt * 16 + m] = acc[mt][nt][r];
    }
    __syncthreads();

    // final: each thread reduces 2 (t,e) pairs in fixed strip order, + bias
    {
        const int t = (tid * 2) >> 6;
        const int e = (tid * 2) & 63;
        float s0 = red[0][t][e], s1 = red[0][t][e + 1];
        #pragma unroll
        for (int s = 1; s < 8; ++s) { s0 += red[s][t][e]; s1 += red[s][t][e + 1]; }
        s0 += bias[e]; s1 += bias[e + 1];
        *reinterpret_cast<float2*>(&logits[(size_t)(t0 + t) * NE + e]) =
            make_float2(s0, s1);
        lbuf[t][e] = s0; lbuf[t][e + 1] = s1;
    }
    __syncthreads();

    // stats: wave w handles tokens 2w, 2w+1; lane = expert
    #pragma unroll
    for (int tt = 0; tt < 2; ++tt) {
        const int t = w * 2 + tt;
        const float lv = lbuf[t][l];
        float v1 = lv; int i1 = l; float v2 = -INFINITY;
        #pragma unroll
        for (int off = 32; off; off >>= 1) {
            const float ov1 = __shfl_xor(v1, off);
            const int   oi1 = __shfl_xor(i1, off);
            const float ov2 = __shfl_xor(v2, off);
            if (ov1 > v1 || (ov1 == v1 && oi1 < i1)) {
                v2 = fmaxf(v1, ov2); v1 = ov1; i1 = oi1;
            } else {
                v2 = fmaxf(v2, ov1);
            }
        }
        float s = expf(lv - v1);
        #pragma unroll
        for (int off = 32; off; off >>= 1) s += __shfl_xor(s, off);
        if (l == 0) {
            const int row = t0 + t;
            maxv[row]   = v1;
            denomv[row] = s;
            c1[row]     = i1;
            w1f[row]    = 1.0f / s;
            atomicAdd(&ghist[i1], 1);
            if (v1 - v2 < THETA) {
                const int ix = atomicAdd(nflag, 1);
                flagl[ix] = row;
            }
        }
    }
}

// Exact fp32 recompute for gap-flagged tokens (coalesced wt [k][e] reads);
// adjusts ghist when the top-1 choice changes.
__global__ __launch_bounds__(256)
void k_exact(const int* __restrict__ nflag, const int* __restrict__ flagl,
             const float* __restrict__ x, const float* __restrict__ wt,
             const float* __restrict__ bias, float* __restrict__ logits,
             float* __restrict__ maxv, float* __restrict__ denomv,
             float* __restrict__ w1f, int* __restrict__ c1,
             int* __restrict__ ghist) {
    __shared__ float part[4][68];
    const int n   = nflag[0];
    const int tid = threadIdx.x;
    const int w   = tid >> 6, l = tid & 63;
    for (int i = blockIdx.x; i < n; i += 64) {
        const int t = flagl[i];
        const float* xr = x + (size_t)t * DIM + w * 512;
        const float* wb = wt + (size_t)(w * 512) * NE + l;
        float a = 0.0f;
        for (int k = 0; k < 512; k += 4) {
            const float4 xv = *reinterpret_cast<const float4*>(xr + k);
            a = fmaf(xv.x, wb[(size_t)(k + 0) * NE], a);
            a = fmaf(xv.y, wb[(size_t)(k + 1) * NE], a);
            a = fmaf(xv.z, wb[(size_t)(k + 2) * NE], a);
            a = fmaf(xv.w, wb[(size_t)(k + 3) * NE], a);
        }
        part[w][l] = a;
        __syncthreads();
        if (w == 0) {
            float lg = bias[l];
            #pragma unroll
            for (int s = 0; s < 4; ++s) lg += part[s][l];
            logits[(size_t)t * NE + l] = lg;
            float v = lg; int idx = l;
            #pragma unroll
            for (int off = 32; off; off >>= 1) {
                const float ov = __shfl_xor(v, off);
                const int   oi = __shfl_xor(idx, off);
                if (ov > v || (ov == v && oi < idx)) { v = ov; idx = oi; }
            }
            float p = expf(lg - v);
            #pragma unroll
            for (int off = 32; off; off >>= 1) p += __shfl_xor(p, off);
            if (l == 0) {
                const int old = c1[t];
                maxv[t]   = v;
                denomv[t] = p;
                c1[t]     = idx;
                w1f[t]    = 1.0f / p;
                if (idx != old) {
                    atomicAdd(&ghist[old], -1);
                    atomicAdd(&ghist[idx], 1);
                }
            }
        }
        __syncthreads();
    }
}

// read 64-entry global histogram -> capacity flag -> fast write or fallback
__global__ __launch_bounds__(256)
void k_decide(const int* __restrict__ c1, const float* __restrict__ w1,
              const float* __restrict__ logits, const float* __restrict__ maxv,
              const float* __restrict__ denomv, const int* __restrict__ tc,
              const int* __restrict__ ghist, float* __restrict__ out,
              float* __restrict__ wtmp) {
    __shared__ int flagS;
    const int tid = threadIdx.x;
    const int cap = tc[0] / TOPK;
    if (tid < NE) {
        const bool bad = (TOPK * ghist[tid] > cap);
        const unsigned long long mm = __ballot(bad);
        if (tid == 0) flagS = (mm == 0ull) ? 1 : 0;
    }
    __syncthreads();

    if (flagS) {
        const int b = blockIdx.x * 256 + tid;
        const float se = (float)c1[b];
        const float wv = w1[b];
        const float wn = wv / (4.0f * wv + 1e-8f);
        *reinterpret_cast<float4*>(out + (size_t)b * 4) = make_float4(se, se, se, se);
        *reinterpret_cast<float4*>(out + (size_t)N_TOK * TOPK + (size_t)b * 4) =
            make_float4(wn, wn, wn, wn);
        return;
    }

    if (blockIdx.x != 0) return;
    if (tid < 64) {
        const int e = tid;
        int rem = cap;
        for (int k = 0; k < TOPK; ++k) {
            for (int b = 0; b < N_TOK; ++b) {
                const float lg = logits[(size_t)b * NE + e];
                float v = (rem > 0) ? lg : -INFINITY;
                int idx = e;
                #pragma unroll
                for (int off = 32; off; off >>= 1) {
                    const float ov = __shfl_xor(v, off);
                    const int   oi = __shfl_xor(idx, off);
                    if (ov > v || (ov == v && oi < idx)) { v = ov; idx = oi; }
                }
                const bool ok = (v != -INFINITY);
                if (ok && e == idx) rem -= 1;
                const float lc = __shfl(lg, idx);
                if (e == 0) {
                    out[(size_t)b * TOPK + k]  = ok ? (float)idx : -1.0f;
                    wtmp[(size_t)b * TOPK + k] = ok ? expf(lc - maxv[b]) / denomv[b] : 0.0f;
                }
            }
        }
    }
    __syncthreads();
    for (int b = tid; b < N_TOK; b += 256) {
        const float w0 = wtmp[b * 4 + 0], w1_ = wtmp[b * 4 + 1];
        const float w2 = wtmp[b * 4 + 2], w3 = wtmp[b * 4 + 3];
        const float s = ((w0 + w1_) + w2) + w3 + 1e-8f;
        out[N_TOK * TOPK + b * 4 + 0] = w0 / s;
        out[N_TOK * TOPK + b * 4 + 1] = w1_ / s;
        out[N_TOK * TOPK + b * 4 + 2] = w2 / s;
        out[N_TOK * TOPK + b * 4 + 3] = w3 / s;
    }
}

extern "C" void kernel_launch(void* const* d_in, const int* in_sizes, int n_in,
                              void* d_out, int out_size, void* d_ws, size_t ws_size,
                              hipStream_t stream) {
    const float* x    = (const float*)d_in[0];
    const float* W    = (const float*)d_in[1];
    const float* bias = (const float*)d_in[2];
    const int*   tc   = (const int*)d_in[3];

    float* ws       = (float*)d_ws;
    float* logits   = ws + OFF_LOGITS;
    float* maxv     = ws + OFF_MAXV;
    float* denomv   = ws + OFF_DENOM;
    float* w1f      = ws + OFF_W1;
    int*   c1       = (int*)(ws + OFF_C1);
    int*   nflag    = (int*)(ws + OFF_NFLAG);
    int*   ghist    = (int*)(ws + OFF_GHIST);
    int*   flagl    = (int*)(ws + OFF_FLAGL);
    unsigned short* wh2 = (unsigned short*)(ws + OFF_WH);
    unsigned short* wl2 = (unsigned short*)(ws + OFF_WL);
    float* wt       = ws + OFF_WT;
    float* wtmp     = ws + OFF_WTMP;
    float* out      = (float*)d_out;

    k_wc<<<NE * DIM / 8 / 256, 256, 0, stream>>>(W, wh2, wl2, wt, nflag, ghist);
    k_main<<<NBLK, 1024, 0, stream>>>(x, wh2, wl2, bias, logits, maxv, denomv,
                                      w1f, c1, nflag, flagl, ghist);
    k_exact<<<64, 256, 0, stream>>>(nflag, flagl, x, wt, bias, logits,
                                    maxv, denomv, w1f, c1, ghist);
    k_decide<<<N_TOK / 256, 256, 0, stream>>>(c1, w1f, logits, maxv, denomv,
                                              tc, ghist, out, wtmp);
}

// Round 7
// 155.474 us; speedup vs baseline: 1.1422x; 1.1422x over previous
//
#include <hip/hip_runtime.h>
#include <math.h>

#define N_TOK 8192
#define DIM   2048
#define NE    64
#define TOPK  4
#define THETA 2e-3f
#define TPB2  16                      /* tokens per k_main block */
#define NBLK  (N_TOK / TPB2)          /* 512 */
#define RSTR  260                     /* padded LDS row stride (floats) */

typedef short bf16x8 __attribute__((ext_vector_type(8)));
typedef float f32x4  __attribute__((ext_vector_type(4)));

// ---- workspace layout (float offsets) ----
#define OFF_LOGITS 0                          /* N_TOK*NE = 524288 */
#define OFF_MAXV   (OFF_LOGITS + N_TOK * NE)
#define OFF_DENOM  (OFF_MAXV + N_TOK)
#define OFF_W1     (OFF_DENOM + N_TOK)
#define OFF_C1     (OFF_W1 + N_TOK)           /* int */
#define OFF_NFLAG  (OFF_C1 + N_TOK)           /* int (padded 64) */
#define OFF_GHIST  (OFF_NFLAG + 64)           /* int, NE (padded 64) */
#define OFF_FLAGL  (OFF_GHIST + 64)           /* int, N_TOK */
#define OFF_WH     (OFF_FLAGL + N_TOK)        /* NE*DIM bf16, frag-packed */
#define OFF_WL     (OFF_WH + NE * DIM / 2)
#define OFF_WT     (OFF_WL + NE * DIM / 2)    /* NE*DIM fp32 transposed */
#define OFF_WTMP   (OFF_WT + NE * DIM)        /* N_TOK*TOPK */

// pack 2 fp32 -> 2 truncated bf16 (hi) and 2 truncated bf16 of residual (lo)
__device__ inline void cvt2(float a, float b, unsigned& hi, unsigned& lo) {
    const unsigned ua = __float_as_uint(a), ub = __float_as_uint(b);
    hi = __builtin_amdgcn_perm(ub, ua, 0x07060302u);   // [a_hi16, b_hi16]
    const float ra = a - __uint_as_float(ua & 0xFFFF0000u);
    const float rb = b - __uint_as_float(ub & 0xFFFF0000u);
    lo = __builtin_amdgcn_perm(__float_as_uint(rb), __float_as_uint(ra), 0x07060302u);
}

union FragU { unsigned u[4]; bf16x8 v; uint4 q; };

__device__ inline void make_frags(const float4& p, const float4& q,
                                  bf16x8& hi, bf16x8& lo) {
    FragU H, L;
    cvt2(p.x, p.y, H.u[0], L.u[0]);
    cvt2(p.z, p.w, H.u[1], L.u[1]);
    cvt2(q.x, q.y, H.u[2], L.u[2]);
    cvt2(q.z, q.w, H.u[3], L.u[3]);
    hi = H.v; lo = L.v;
}

// W -> frag-packed (wh2, wl2): element for (kc, nt, lane, j) is
// W[e = nt*16 + (lane&15)][k = kc*32 + (lane>>4)*8 + j] at elem offset
// (kc*4+nt)*512 + lane*8 + j  -> B loads are contiguous 1KB/wave.
// Also wt fp32 transpose [k][e]; zero nflag/ghist.
__global__ __launch_bounds__(256)
void k_wc(const float* __restrict__ W, unsigned short* __restrict__ wh2,
          unsigned short* __restrict__ wl2, float* __restrict__ wt,
          int* __restrict__ nflag, int* __restrict__ ghist) {
    const int t = blockIdx.x * 256 + threadIdx.x;     // 0..16383
    if (t < NE) ghist[t] = 0;
    if (t == NE) nflag[0] = 0;
    const int l  = t & 63;
    const int grp = t >> 6;                           // = kc*4 + nt, 0..255
    const int nt = grp & 3;
    const int kc = grp >> 2;
    const int e  = nt * 16 + (l & 15);
    const int k0 = kc * 32 + (l >> 4) * 8;

    const float4 p = *reinterpret_cast<const float4*>(W + (size_t)e * DIM + k0);
    const float4 q = *reinterpret_cast<const float4*>(W + (size_t)e * DIM + k0 + 4);
    FragU H, L;
    cvt2(p.x, p.y, H.u[0], L.u[0]);
    cvt2(p.z, p.w, H.u[1], L.u[1]);
    cvt2(q.x, q.y, H.u[2], L.u[2]);
    cvt2(q.z, q.w, H.u[3], L.u[3]);
    const size_t off = (size_t)grp * 512 + l * 8;
    *reinterpret_cast<uint4*>(wh2 + off) = H.q;
    *reinterpret_cast<uint4*>(wl2 + off) = L.q;

    wt[(size_t)(k0 + 0) * NE + e] = p.x;
    wt[(size_t)(k0 + 1) * NE + e] = p.y;
    wt[(size_t)(k0 + 2) * NE + e] = p.z;
    wt[(size_t)(k0 + 3) * NE + e] = p.w;
    wt[(size_t)(k0 + 4) * NE + e] = q.x;
    wt[(size_t)(k0 + 5) * NE + e] = q.y;
    wt[(size_t)(k0 + 6) * NE + e] = q.z;
    wt[(size_t)(k0 + 7) * NE + e] = q.w;
}

// Fused split-bf16 MFMA GEMM + stats. 512 thr (8 waves), 16 tokens.
// Window = 256 k staged in LDS (double-buffered); wave w consumes k-chunk
// win*256 + w*32. B from frag-packed global (contiguous 1KB loads, L2-hot).
// 3 MFMA products (al*bl dropped, ~4e-6 << THETA/2).
// LDS overlay: red[] reuses the xs staging buffer (dead after K-loop) ->
// 39.2 KB total -> 4 blocks/CU (32 waves/CU).
__global__ __launch_bounds__(512, 4)
void k_main(const float* __restrict__ x, const unsigned short* __restrict__ wh2,
            const unsigned short* __restrict__ wl2, const float* __restrict__ bias,
            float* __restrict__ logits, float* __restrict__ maxv,
            float* __restrict__ denomv, float* __restrict__ w1f,
            int* __restrict__ c1, int* __restrict__ nflag, int* __restrict__ flagl,
            int* __restrict__ ghist) {
    // pool: [0, 8320) = xs (2 x 16 x 260); overlaid [0, 8704) = red (8x16x68);
    //       [8704, 9792) = lbuf (16 x 68).  Total 39168 B.
    __shared__ __align__(16) float pool[9792];
    float* xs   = pool;
    float* red  = pool;
    float* lbuf = pool + 8704;

    const int tid = threadIdx.x;
    const int w   = tid >> 6;            // wave 0..7
    const int l   = tid & 63;
    const int t0  = blockIdx.x * TPB2;
    const int m   = l & 15;              // token (A) / expert-low (B)
    const int g   = l >> 4;              // k-octet group

    // staging: wave w owns token rows 2w, 2w+1; lane covers 16B of the row
    const float* xrow0 = x + (size_t)(t0 + 2 * w) * DIM + l * 4;
    const float* xrow1 = x + (size_t)(t0 + 2 * w + 1) * DIM + l * 4;
    float* st0 = &xs[(2 * w) * RSTR + l * 4];
    float* st1 = &xs[(2 * w + 1) * RSTR + l * 4];
    const int xs1off = TPB2 * RSTR;      // second buffer offset (4160)

    // B: elem offset (kc*4+nt)*512 + l*8, kc = win*8 + w
    const unsigned short* bh = wh2 + (size_t)w * 2048 + l * 8;
    const unsigned short* bl = wl2 + (size_t)w * 2048 + l * 8;

    f32x4 accA[4], accB[4];
    #pragma unroll
    for (int nt = 0; nt < 4; ++nt)
        #pragma unroll
        for (int r = 0; r < 4; ++r) { accA[nt][r] = 0.0f; accB[nt][r] = 0.0f; }

    // prologue: stage window 0, preload B window 0
    {
        const float4 r0 = *reinterpret_cast<const float4*>(xrow0);
        const float4 r1 = *reinterpret_cast<const float4*>(xrow1);
        *reinterpret_cast<float4*>(st0) = r0;
        *reinterpret_cast<float4*>(st1) = r1;
    }
    uint4 BH[2][4], BL[2][4];
    #pragma unroll
    for (int nt = 0; nt < 4; ++nt) {
        BH[0][nt] = *reinterpret_cast<const uint4*>(bh + nt * 512);
        BL[0][nt] = *reinterpret_cast<const uint4*>(bl + nt * 512);
    }
    __syncthreads();

    const int aoff = m * RSTR + w * 32 + g * 8;   // A frag base in window

    #pragma unroll
    for (int win = 0; win < 8; ++win) {
        const int cur = win & 1, nxt = cur ^ 1;
        float4 nx0, nx1;
        if (win < 7) {
            nx0 = *reinterpret_cast<const float4*>(xrow0 + (win + 1) * 256);
            nx1 = *reinterpret_cast<const float4*>(xrow1 + (win + 1) * 256);
            #pragma unroll
            for (int nt = 0; nt < 4; ++nt) {
                BH[nxt][nt] = *reinterpret_cast<const uint4*>(
                    bh + (size_t)(win + 1) * 16384 + nt * 512);
                BL[nxt][nt] = *reinterpret_cast<const uint4*>(
                    bl + (size_t)(win + 1) * 16384 + nt * 512);
            }
        }

        const float4 p = *reinterpret_cast<const float4*>(&xs[cur * xs1off + aoff]);
        const float4 q = *reinterpret_cast<const float4*>(&xs[cur * xs1off + aoff + 4]);
        bf16x8 ah, al;
        make_frags(p, q, ah, al);

        #pragma unroll
        for (int nt = 0; nt < 4; ++nt) {
            FragU b; b.q = BH[cur][nt];
            accA[nt] = __builtin_amdgcn_mfma_f32_16x16x32_bf16(ah, b.v, accA[nt], 0, 0, 0);
            accB[nt] = __builtin_amdgcn_mfma_f32_16x16x32_bf16(al, b.v, accB[nt], 0, 0, 0);
        }
        #pragma unroll
        for (int nt = 0; nt < 4; ++nt) {
            FragU b; b.q = BL[cur][nt];
            accB[nt] = __builtin_amdgcn_mfma_f32_16x16x32_bf16(ah, b.v, accB[nt], 0, 0, 0);
        }

        if (win < 7) {
            *reinterpret_cast<float4*>(st0 + nxt * xs1off) = nx0;
            *reinterpret_cast<float4*>(st1 + nxt * xs1off) = nx1;
        }
        __syncthreads();   // also separates last MFMA xs-reads from red overlay
    }

    // red overlay begins (xs dead)
    #pragma unroll
    for (int nt = 0; nt < 4; ++nt)
        #pragma unroll
        for (int r = 0; r < 4; ++r)
            red[(w * TPB2 + g * 4 + r) * 68 + nt * 16 + m] = accA[nt][r] + accB[nt][r];
    __syncthreads();

    for (int e2 = tid; e2 < TPB2 * NE; e2 += 512) {
        const int t = e2 >> 6, e = e2 & 63;
        float s = red[(0 * TPB2 + t) * 68 + e];
        #pragma unroll
        for (int ww = 1; ww < 8; ++ww) s += red[(ww * TPB2 + t) * 68 + e];
        s += bias[e];
        logits[(size_t)(t0 + t) * NE + e] = s;
        lbuf[t * 68 + e] = s;
    }
    __syncthreads();

    // stats: wave w handles tokens 2w, 2w+1; lane = expert
    #pragma unroll
    for (int tt = 0; tt < 2; ++tt) {
        const int t = w * 2 + tt;
        const float lv = lbuf[t * 68 + l];
        float v1 = lv; int i1 = l; float v2 = -INFINITY;
        #pragma unroll
        for (int off = 32; off; off >>= 1) {
            const float ov1 = __shfl_xor(v1, off);
            const int   oi1 = __shfl_xor(i1, off);
            const float ov2 = __shfl_xor(v2, off);
            if (ov1 > v1 || (ov1 == v1 && oi1 < i1)) {
                v2 = fmaxf(v1, ov2); v1 = ov1; i1 = oi1;
            } else {
                v2 = fmaxf(v2, ov1);
            }
        }
        float s = expf(lv - v1);
        #pragma unroll
        for (int off = 32; off; off >>= 1) s += __shfl_xor(s, off);
        if (l == 0) {
            const int row = t0 + t;
            maxv[row]   = v1;
            denomv[row] = s;
            c1[row]     = i1;
            w1f[row]    = 1.0f / s;
            atomicAdd(&ghist[i1], 1);
            if (v1 - v2 < THETA) {
                const int ix = atomicAdd(nflag, 1);
                flagl[ix] = row;
            }
        }
    }
}

// Exact fp32 recompute for gap-flagged tokens (coalesced wt [k][e] reads);
// adjusts ghist when the top-1 choice changes.
__global__ __launch_bounds__(256)
void k_exact(const int* __restrict__ nflag, const int* __restrict__ flagl,
             const float* __restrict__ x, const float* __restrict__ wt,
             const float* __restrict__ bias, float* __restrict__ logits,
             float* __restrict__ maxv, float* __restrict__ denomv,
             float* __restrict__ w1f, int* __restrict__ c1,
             int* __restrict__ ghist) {
    __shared__ float part[4][68];
    const int n   = nflag[0];
    const int tid = threadIdx.x;
    const int w   = tid >> 6, l = tid & 63;
    for (int i = blockIdx.x; i < n; i += 64) {
        const int t = flagl[i];
        const float* xr = x + (size_t)t * DIM + w * 512;
        const float* wb = wt + (size_t)(w * 512) * NE + l;
        float a = 0.0f;
        for (int k = 0; k < 512; k += 4) {
            const float4 xv = *reinterpret_cast<const float4*>(xr + k);
            a = fmaf(xv.x, wb[(size_t)(k + 0) * NE], a);
            a = fmaf(xv.y, wb[(size_t)(k + 1) * NE], a);
            a = fmaf(xv.z, wb[(size_t)(k + 2) * NE], a);
            a = fmaf(xv.w, wb[(size_t)(k + 3) * NE], a);
        }
        part[w][l] = a;
        __syncthreads();
        if (w == 0) {
            float lg = bias[l];
            #pragma unroll
            for (int s = 0; s < 4; ++s) lg += part[s][l];
            logits[(size_t)t * NE + l] = lg;
            float v = lg; int idx = l;
            #pragma unroll
            for (int off = 32; off; off >>= 1) {
                const float ov = __shfl_xor(v, off);
                const int   oi = __shfl_xor(idx, off);
                if (ov > v || (ov == v && oi < idx)) { v = ov; idx = oi; }
            }
            float p = expf(lg - v);
            #pragma unroll
            for (int off = 32; off; off >>= 1) p += __shfl_xor(p, off);
            if (l == 0) {
                const int old = c1[t];
                maxv[t]   = v;
                denomv[t] = p;
                c1[t]     = idx;
                w1f[t]    = 1.0f / p;
                if (idx != old) {
                    atomicAdd(&ghist[old], -1);
                    atomicAdd(&ghist[idx], 1);
                }
            }
        }
        __syncthreads();
    }
}

// read 64-entry global histogram -> capacity flag -> fast write or fallback
__global__ __launch_bounds__(256)
void k_decide(const int* __restrict__ c1, const float* __restrict__ w1,
              const float* __restrict__ logits, const float* __restrict__ maxv,
              const float* __restrict__ denomv, const int* __restrict__ tc,
              const int* __restrict__ ghist, float* __restrict__ out,
              float* __restrict__ wtmp) {
    __shared__ int flagS;
    const int tid = threadIdx.x;
    const int cap = tc[0] / TOPK;
    if (tid < NE) {
        const bool bad = (TOPK * ghist[tid] > cap);
        const unsigned long long mm = __ballot(bad);
        if (tid == 0) flagS = (mm == 0ull) ? 1 : 0;
    }
    __syncthreads();

    if (flagS) {
        const int b = blockIdx.x * 256 + tid;
        const float se = (float)c1[b];
        const float wv = w1[b];
        const float wn = wv / (4.0f * wv + 1e-8f);
        *reinterpret_cast<float4*>(out + (size_t)b * 4) = make_float4(se, se, se, se);
        *reinterpret_cast<float4*>(out + (size_t)N_TOK * TOPK + (size_t)b * 4) =
            make_float4(wn, wn, wn, wn);
        return;
    }

    if (blockIdx.x != 0) return;
    if (tid < 64) {
        const int e = tid;
        int rem = cap;
        for (int k = 0; k < TOPK; ++k) {
            for (int b = 0; b < N_TOK; ++b) {
                const float lg = logits[(size_t)b * NE + e];
                float v = (rem > 0) ? lg : -INFINITY;
                int idx = e;
                #pragma unroll
                for (int off = 32; off; off >>= 1) {
                    const float ov = __shfl_xor(v, off);
                    const int   oi = __shfl_xor(idx, off);
                    if (ov > v || (ov == v && oi < idx)) { v = ov; idx = oi; }
                }
                const bool ok = (v != -INFINITY);
                if (ok && e == idx) rem -= 1;
                const float lc = __shfl(lg, idx);
                if (e == 0) {
                    out[(size_t)b * TOPK + k]  = ok ? (float)idx : -1.0f;
                    wtmp[(size_t)b * TOPK + k] = ok ? expf(lc - maxv[b]) / denomv[b] : 0.0f;
                }
            }
        }
    }
    __syncthreads();
    for (int b = tid; b < N_TOK; b += 256) {
        const float w0 = wtmp[b * 4 + 0], w1_ = wtmp[b * 4 + 1];
        const float w2 = wtmp[b * 4 + 2], w3 = wtmp[b * 4 + 3];
        const float s = ((w0 + w1_) + w2) + w3 + 1e-8f;
        out[N_TOK * TOPK + b * 4 + 0] = w0 / s;
        out[N_TOK * TOPK + b * 4 + 1] = w1_ / s;
        out[N_TOK * TOPK + b * 4 + 2] = w2 / s;
        out[N_TOK * TOPK + b * 4 + 3] = w3 / s;
    }
}

extern "C" void kernel_launch(void* const* d_in, const int* in_sizes, int n_in,
                              void* d_out, int out_size, void* d_ws, size_t ws_size,
                              hipStream_t stream) {
    const float* x    = (const float*)d_in[0];
    const float* W    = (const float*)d_in[1];
    const float* bias = (const float*)d_in[2];
    const int*   tc   = (const int*)d_in[3];

    float* ws       = (float*)d_ws;
    float* logits   = ws + OFF_LOGITS;
    float* maxv     = ws + OFF_MAXV;
    float* denomv   = ws + OFF_DENOM;
    float* w1f      = ws + OFF_W1;
    int*   c1       = (int*)(ws + OFF_C1);
    int*   nflag    = (int*)(ws + OFF_NFLAG);
    int*   ghist    = (int*)(ws + OFF_GHIST);
    int*   flagl    = (int*)(ws + OFF_FLAGL);
    unsigned short* wh2 = (unsigned short*)(ws + OFF_WH);
    unsigned short* wl2 = (unsigned short*)(ws + OFF_WL);
    float* wt       = ws + OFF_WT;
    float* wtmp     = ws + OFF_WTMP;
    float* out      = (float*)d_out;

    k_wc<<<NE * DIM / 8 / 256, 256, 0, stream>>>(W, wh2, wl2, wt, nflag, ghist);
    k_main<<<NBLK, 512, 0, stream>>>(x, wh2, wl2, bias, logits, maxv, denomv,
                                     w1f, c1, nflag, flagl, ghist);
    k_exact<<<64, 256, 0, stream>>>(nflag, flagl, x, wt, bias, logits,
                                    maxv, denomv, w1f, c1, ghist);
    k_decide<<<N_TOK / 256, 256, 0, stream>>>(c1, w1f, logits, maxv, denomv,
                                              tc, ghist, out, wtmp);
}

// Round 8
// 132.371 us; speedup vs baseline: 1.3415x; 1.1745x over previous
//
#include <hip/hip_runtime.h>
#include <math.h>

#define N_TOK 8192
#define DIM   2048
#define NE    64
#define TOPK  4
#define THETA 2e-3f
#define TPB2  16                      /* tokens per k_main block */
#define NBLK  (N_TOK / TPB2)          /* 512 */
#define RSTR  260                     /* padded LDS row stride (floats) */

typedef short bf16x8 __attribute__((ext_vector_type(8)));
typedef float f32x4  __attribute__((ext_vector_type(4)));

#define AS1 __attribute__((address_space(1)))
#define AS3 __attribute__((address_space(3)))

// ---- workspace layout (float offsets) ----
#define OFF_LOGITS 0                          /* N_TOK*NE = 524288 */
#define OFF_MAXV   (OFF_LOGITS + N_TOK * NE)
#define OFF_DENOM  (OFF_MAXV + N_TOK)
#define OFF_W1     (OFF_DENOM + N_TOK)
#define OFF_C1     (OFF_W1 + N_TOK)           /* int */
#define OFF_NFLAG  (OFF_C1 + N_TOK)           /* int (padded 64) */
#define OFF_FLAGL  (OFF_NFLAG + 64)           /* int, N_TOK */
#define OFF_WH     (OFF_FLAGL + N_TOK)        /* NE*DIM bf16, frag-packed */
#define OFF_WL     (OFF_WH + NE * DIM / 2)
#define OFF_WT     (OFF_WL + NE * DIM / 2)    /* NE*DIM fp32 transposed */
#define OFF_WTMP   (OFF_WT + NE * DIM)        /* N_TOK*TOPK */

// pack 2 fp32 -> 2 truncated bf16 (hi) and 2 truncated bf16 of residual (lo)
__device__ inline void cvt2(float a, float b, unsigned& hi, unsigned& lo) {
    const unsigned ua = __float_as_uint(a), ub = __float_as_uint(b);
    hi = __builtin_amdgcn_perm(ub, ua, 0x07060302u);   // [a_hi16, b_hi16]
    const float ra = a - __uint_as_float(ua & 0xFFFF0000u);
    const float rb = b - __uint_as_float(ub & 0xFFFF0000u);
    lo = __builtin_amdgcn_perm(__float_as_uint(rb), __float_as_uint(ra), 0x07060302u);
}

union FragU { unsigned u[4]; bf16x8 v; uint4 q; };

__device__ inline void make_frags(const float4& p, const float4& q,
                                  bf16x8& hi, bf16x8& lo) {
    FragU H, L;
    cvt2(p.x, p.y, H.u[0], L.u[0]);
    cvt2(p.z, p.w, H.u[1], L.u[1]);
    cvt2(q.x, q.y, H.u[2], L.u[2]);
    cvt2(q.z, q.w, H.u[3], L.u[3]);
    hi = H.v; lo = L.v;
}

// W -> frag-packed (wh2, wl2): element for (kc, nt, lane, j) is
// W[e = nt*16 + (lane&15)][k = kc*32 + (lane>>4)*8 + j] at elem offset
// (kc*4+nt)*512 + lane*8 + j  -> B loads are contiguous 1KB/wave.
// Also wt fp32 transpose [k][e] for k_exact, and nflag zero.
__global__ __launch_bounds__(256)
void k_wc(const float* __restrict__ W, unsigned short* __restrict__ wh2,
          unsigned short* __restrict__ wl2, float* __restrict__ wt,
          int* __restrict__ nflag) {
    const int t = blockIdx.x * 256 + threadIdx.x;     // 0..16383
    if (t == 0) nflag[0] = 0;
    const int l  = t & 63;
    const int grp = t >> 6;                           // = kc*4 + nt, 0..255
    const int nt = grp & 3;
    const int kc = grp >> 2;
    const int e  = nt * 16 + (l & 15);
    const int k0 = kc * 32 + (l >> 4) * 8;

    const float4 p = *reinterpret_cast<const float4*>(W + (size_t)e * DIM + k0);
    const float4 q = *reinterpret_cast<const float4*>(W + (size_t)e * DIM + k0 + 4);
    FragU H, L;
    cvt2(p.x, p.y, H.u[0], L.u[0]);
    cvt2(p.z, p.w, H.u[1], L.u[1]);
    cvt2(q.x, q.y, H.u[2], L.u[2]);
    cvt2(q.z, q.w, H.u[3], L.u[3]);
    const size_t off = (size_t)grp * 512 + l * 8;
    *reinterpret_cast<uint4*>(wh2 + off) = H.q;
    *reinterpret_cast<uint4*>(wl2 + off) = L.q;

    wt[(size_t)(k0 + 0) * NE + e] = p.x;
    wt[(size_t)(k0 + 1) * NE + e] = p.y;
    wt[(size_t)(k0 + 2) * NE + e] = p.z;
    wt[(size_t)(k0 + 3) * NE + e] = p.w;
    wt[(size_t)(k0 + 4) * NE + e] = q.x;
    wt[(size_t)(k0 + 5) * NE + e] = q.y;
    wt[(size_t)(k0 + 6) * NE + e] = q.z;
    wt[(size_t)(k0 + 7) * NE + e] = q.w;
}

// Fused split-bf16 MFMA GEMM + stats. 512 thr (8 waves), 16 tokens.
// Window = 256 k staged in LDS via global_load_lds DMA (double-buffered);
// wave w consumes k-chunk win*256 + w*32. B from frag-packed global
// (contiguous 1KB loads, L2-hot). 3 MFMA products (al*bl dropped).
__global__ __launch_bounds__(512, 4)
void k_main(const float* __restrict__ x, const unsigned short* __restrict__ wh2,
            const unsigned short* __restrict__ wl2, const float* __restrict__ bias,
            float* __restrict__ logits, float* __restrict__ maxv,
            float* __restrict__ denomv, float* __restrict__ w1f,
            int* __restrict__ c1, int* __restrict__ nflag, int* __restrict__ flagl) {
    __shared__ __align__(16) float xs[2][TPB2 * RSTR];   // 33280 B
    __shared__ float red[8][TPB2][68];                    // 34816 B
    __shared__ float lbuf[TPB2][68];                      //  4352 B

    const int tid = threadIdx.x;
    const int w   = tid >> 6;            // wave 0..7
    const int l   = tid & 63;
    const int t0  = blockIdx.x * TPB2;
    const int m   = l & 15;              // token (A) / expert-low (B)
    const int g   = l >> 4;              // k-octet group

    // DMA staging: wave w owns token rows 2w, 2w+1. Per row: lane l reads 16B
    // at row+l*16; HW stores to wave-uniform LDS base + lane*16.
    const float* xrow0 = x + (size_t)(t0 + 2 * w) * DIM + l * 4;
    const float* xrow1 = x + (size_t)(t0 + 2 * w + 1) * DIM + l * 4;
    AS3 float* lds0 = (AS3 float*)&xs[0][(2 * w) * RSTR];
    AS3 float* lds1 = (AS3 float*)&xs[0][(2 * w + 1) * RSTR];
    const int xs1off = TPB2 * RSTR;      // second-buffer offset (floats)

    // B: elem offset (kc*4+nt)*512 + l*8, kc = win*8 + w
    const unsigned short* bh = wh2 + (size_t)w * 2048 + l * 8;
    const unsigned short* bl = wl2 + (size_t)w * 2048 + l * 8;

    f32x4 accA[4], accB[4];
    #pragma unroll
    for (int nt = 0; nt < 4; ++nt)
        #pragma unroll
        for (int r = 0; r < 4; ++r) { accA[nt][r] = 0.0f; accB[nt][r] = 0.0f; }

    // prologue: DMA-stage window 0, preload B window 0
    __builtin_amdgcn_global_load_lds((const AS1 void*)xrow0, (AS3 void*)lds0, 16, 0, 0);
    __builtin_amdgcn_global_load_lds((const AS1 void*)xrow1, (AS3 void*)lds1, 16, 0, 0);
    uint4 BH[2][4], BL[2][4];
    #pragma unroll
    for (int nt = 0; nt < 4; ++nt) {
        BH[0][nt] = *reinterpret_cast<const uint4*>(bh + nt * 512);
        BL[0][nt] = *reinterpret_cast<const uint4*>(bl + nt * 512);
    }
    __syncthreads();

    const int aoff = m * RSTR + w * 32 + g * 8;   // A frag base in window

    #pragma unroll
    for (int win = 0; win < 8; ++win) {
        const int cur = win & 1, nxt = cur ^ 1;
        if (win < 7) {
            // DMA next x window into the other buffer (read in win-1, barrier-safe)
            __builtin_amdgcn_global_load_lds(
                (const AS1 void*)(xrow0 + (win + 1) * 256),
                (AS3 void*)(lds0 + nxt * xs1off), 16, 0, 0);
            __builtin_amdgcn_global_load_lds(
                (const AS1 void*)(xrow1 + (win + 1) * 256),
                (AS3 void*)(lds1 + nxt * xs1off), 16, 0, 0);
            #pragma unroll
            for (int nt = 0; nt < 4; ++nt) {
                BH[nxt][nt] = *reinterpret_cast<const uint4*>(
                    bh + (size_t)(win + 1) * 16384 + nt * 512);
                BL[nxt][nt] = *reinterpret_cast<const uint4*>(
                    bl + (size_t)(win + 1) * 16384 + nt * 512);
            }
        }

        const float4 p = *reinterpret_cast<const float4*>(&xs[0][cur * xs1off + aoff]);
        const float4 q = *reinterpret_cast<const float4*>(&xs[0][cur * xs1off + aoff + 4]);
        bf16x8 ah, al;
        make_frags(p, q, ah, al);

        #pragma unroll
        for (int nt = 0; nt < 4; ++nt) {
            FragU b; b.q = BH[cur][nt];
            accA[nt] = __builtin_amdgcn_mfma_f32_16x16x32_bf16(ah, b.v, accA[nt], 0, 0, 0);
            accB[nt] = __builtin_amdgcn_mfma_f32_16x16x32_bf16(al, b.v, accB[nt], 0, 0, 0);
        }
        #pragma unroll
        for (int nt = 0; nt < 4; ++nt) {
            FragU b; b.q = BL[cur][nt];
            accB[nt] = __builtin_amdgcn_mfma_f32_16x16x32_bf16(ah, b.v, accB[nt], 0, 0, 0);
        }
        __syncthreads();
    }

    #pragma unroll
    for (int nt = 0; nt < 4; ++nt)
        #pragma unroll
        for (int r = 0; r < 4; ++r)
            red[w][g * 4 + r][nt * 16 + m] = accA[nt][r] + accB[nt][r];
    __syncthreads();

    for (int e2 = tid; e2 < TPB2 * NE; e2 += 512) {
        const int t = e2 >> 6, e = e2 & 63;
        float s = red[0][t][e];
        #pragma unroll
        for (int ww = 1; ww < 8; ++ww) s += red[ww][t][e];
        s += bias[e];
        logits[(size_t)(t0 + t) * NE + e] = s;
        lbuf[t][e] = s;
    }
    __syncthreads();

    // stats: wave w handles tokens 2w, 2w+1; lane = expert
    #pragma unroll
    for (int tt = 0; tt < 2; ++tt) {
        const int t = w * 2 + tt;
        const float lv = lbuf[t][l];
        float v1 = lv; int i1 = l; float v2 = -INFINITY;
        #pragma unroll
        for (int off = 32; off; off >>= 1) {
            const float ov1 = __shfl_xor(v1, off);
            const int   oi1 = __shfl_xor(i1, off);
            const float ov2 = __shfl_xor(v2, off);
            if (ov1 > v1 || (ov1 == v1 && oi1 < i1)) {
                v2 = fmaxf(v1, ov2); v1 = ov1; i1 = oi1;
            } else {
                v2 = fmaxf(v2, ov1);
            }
        }
        float s = expf(lv - v1);
        #pragma unroll
        for (int off = 32; off; off >>= 1) s += __shfl_xor(s, off);
        if (l == 0) {
            const int row = t0 + t;
            maxv[row]   = v1;
            denomv[row] = s;
            c1[row]     = i1;
            w1f[row]    = 1.0f / s;
            if (v1 - v2 < THETA) {
                const int ix = atomicAdd(nflag, 1);
                flagl[ix] = row;
            }
        }
    }
}

// Exact fp32 recompute for gap-flagged tokens (coalesced wt [k][e] reads).
__global__ __launch_bounds__(256)
void k_exact(const int* __restrict__ nflag, const int* __restrict__ flagl,
             const float* __restrict__ x, const float* __restrict__ wt,
             const float* __restrict__ bias, float* __restrict__ logits,
             float* __restrict__ maxv, float* __restrict__ denomv,
             float* __restrict__ w1f, int* __restrict__ c1) {
    __shared__ float part[4][68];
    const int n   = nflag[0];
    const int tid = threadIdx.x;
    const int w   = tid >> 6, l = tid & 63;
    for (int i = blockIdx.x; i < n; i += 64) {
        const int t = flagl[i];
        const float* xr = x + (size_t)t * DIM + w * 512;
        const float* wb = wt + (size_t)(w * 512) * NE + l;
        float a = 0.0f;
        for (int k = 0; k < 512; k += 4) {
            const float4 xv = *reinterpret_cast<const float4*>(xr + k);
            a = fmaf(xv.x, wb[(size_t)(k + 0) * NE], a);
            a = fmaf(xv.y, wb[(size_t)(k + 1) * NE], a);
            a = fmaf(xv.z, wb[(size_t)(k + 2) * NE], a);
            a = fmaf(xv.w, wb[(size_t)(k + 3) * NE], a);
        }
        part[w][l] = a;
        __syncthreads();
        if (w == 0) {
            float lg = bias[l];
            #pragma unroll
            for (int s = 0; s < 4; ++s) lg += part[s][l];
            logits[(size_t)t * NE + l] = lg;
            float v = lg; int idx = l;
            #pragma unroll
            for (int off = 32; off; off >>= 1) {
                const float ov = __shfl_xor(v, off);
                const int   oi = __shfl_xor(idx, off);
                if (ov > v || (ov == v && oi < idx)) { v = ov; idx = oi; }
            }
            float p = expf(lg - v);
            #pragma unroll
            for (int off = 32; off; off >>= 1) p += __shfl_xor(p, off);
            if (l == 0) {
                maxv[t]   = v;
                denomv[t] = p;
                c1[t]     = idx;
                w1f[t]    = 1.0f / p;
            }
        }
        __syncthreads();
    }
}

// per-block LDS histogram of first choices -> capacity flag -> fast write
// or block-0 exact serial fallback
__global__ __launch_bounds__(256)
void k_decide(const int* __restrict__ c1, const float* __restrict__ w1,
              const float* __restrict__ logits, const float* __restrict__ maxv,
              const float* __restrict__ denomv, const int* __restrict__ tc,
              float* __restrict__ out, float* __restrict__ wtmp) {
    __shared__ int hist[NE];
    __shared__ int flagS;
    const int tid = threadIdx.x;
    if (tid < NE) hist[tid] = 0;
    __syncthreads();
    for (int i = tid; i < N_TOK; i += 256) atomicAdd(&hist[c1[i]], 1);
    __syncthreads();
    const int cap = tc[0] / TOPK;
    if (tid < NE) {
        const bool bad = (TOPK * hist[tid] > cap);
        const unsigned long long mm = __ballot(bad);
        if (tid == 0) flagS = (mm == 0ull) ? 1 : 0;
    }
    __syncthreads();

    if (flagS) {
        const int b = blockIdx.x * 256 + tid;
        const float se = (float)c1[b];
        const float wv = w1[b];
        const float wn = wv / (4.0f * wv + 1e-8f);
        *reinterpret_cast<float4*>(out + (size_t)b * 4) = make_float4(se, se, se, se);
        *reinterpret_cast<float4*>(out + (size_t)N_TOK * TOPK + (size_t)b * 4) =
            make_float4(wn, wn, wn, wn);
        return;
    }

    if (blockIdx.x != 0) return;
    if (tid < 64) {
        const int e = tid;
        int rem = cap;
        for (int k = 0; k < TOPK; ++k) {
            for (int b = 0; b < N_TOK; ++b) {
                const float lg = logits[(size_t)b * NE + e];
                float v = (rem > 0) ? lg : -INFINITY;
                int idx = e;
                #pragma unroll
                for (int off = 32; off; off >>= 1) {
                    const float ov = __shfl_xor(v, off);
                    const int   oi = __shfl_xor(idx, off);
                    if (ov > v || (ov == v && oi < idx)) { v = ov; idx = oi; }
                }
                const bool ok = (v != -INFINITY);
                if (ok && e == idx) rem -= 1;
                const float lc = __shfl(lg, idx);
                if (e == 0) {
                    out[(size_t)b * TOPK + k]  = ok ? (float)idx : -1.0f;
                    wtmp[(size_t)b * TOPK + k] = ok ? expf(lc - maxv[b]) / denomv[b] : 0.0f;
                }
            }
        }
    }
    __syncthreads();
    for (int b = tid; b < N_TOK; b += 256) {
        const float w0 = wtmp[b * 4 + 0], w1_ = wtmp[b * 4 + 1];
        const float w2 = wtmp[b * 4 + 2], w3 = wtmp[b * 4 + 3];
        const float s = ((w0 + w1_) + w2) + w3 + 1e-8f;
        out[N_TOK * TOPK + b * 4 + 0] = w0 / s;
        out[N_TOK * TOPK + b * 4 + 1] = w1_ / s;
        out[N_TOK * TOPK + b * 4 + 2] = w2 / s;
        out[N_TOK * TOPK + b * 4 + 3] = w3 / s;
    }
}

extern "C" void kernel_launch(void* const* d_in, const int* in_sizes, int n_in,
                              void* d_out, int out_size, void* d_ws, size_t ws_size,
                              hipStream_t stream) {
    const float* x    = (const float*)d_in[0];
    const float* W    = (const float*)d_in[1];
    const float* bias = (const float*)d_in[2];
    const int*   tc   = (const int*)d_in[3];

    float* ws       = (float*)d_ws;
    float* logits   = ws + OFF_LOGITS;
    float* maxv     = ws + OFF_MAXV;
    float* denomv   = ws + OFF_DENOM;
    float* w1f      = ws + OFF_W1;
    int*   c1       = (int*)(ws + OFF_C1);
    int*   nflag    = (int*)(ws + OFF_NFLAG);
    int*   flagl    = (int*)(ws + OFF_FLAGL);
    unsigned short* wh2 = (unsigned short*)(ws + OFF_WH);
    unsigned short* wl2 = (unsigned short*)(ws + OFF_WL);
    float* wt       = ws + OFF_WT;
    float* wtmp     = ws + OFF_WTMP;
    float* out      = (float*)d_out;

    k_wc<<<NE * DIM / 8 / 256, 256, 0, stream>>>(W, wh2, wl2, wt, nflag);
    k_main<<<NBLK, 512, 0, stream>>>(x, wh2, wl2, bias, logits, maxv, denomv,
                                     w1f, c1, nflag, flagl);
    k_exact<<<64, 256, 0, stream>>>(nflag, flagl, x, wt, bias, logits,
                                    maxv, denomv, w1f, c1);
    k_decide<<<N_TOK / 256, 256, 0, stream>>>(c1, w1f, logits, maxv, denomv,
                                              tc, out, wtmp);
}